// Round 6
// baseline (183.187 us; speedup 1.0000x reference)
//
#include <hip/hip_runtime.h>
#include <hip/hip_bf16.h>
#include <math.h>

// SupCon loss, N=8192 D=128 fp32 in, scalar fp32 out.
// Round 6: barrier-free sim. MFMA fragments are 16 contiguous bytes in Fb
// (row-major, K=128), so A/B frags load straight from global (L2-resident,
// 2 MB) -- no LDS, no __syncthreads, no atomics in sim. Each wave owns 16
// rows; per-(row,chunk) partials are plain stores; finalize sums depth-8
// partials and builds the label histogram in LDS.
// Fb = f/||f|| * sqrt(10*log2e) -> MFMA acc is log2-domain: exp(sim)=exp2(acc).

constexpr int N = 8192;
constexpr int D = 128;

typedef __attribute__((ext_vector_type(8))) short short8;  // 8 bf16 = 4 VGPRs
typedef __attribute__((ext_vector_type(4))) float f32x4;

__device__ __forceinline__ float fast_exp2(float x) {
#if __has_builtin(__builtin_amdgcn_exp2f)
    return __builtin_amdgcn_exp2f(x);
#else
    return __expf(x * 0.69314718056f);
#endif
}

// ---------------- prep: bf16 rows scaled into log2 domain; zero out ---------
__global__ void prep_kernel(const float* __restrict__ F,
                            unsigned short* __restrict__ Fb,
                            float* __restrict__ out) {
    int row = blockIdx.x * 16 + (threadIdx.x >> 6);  // 512 blocks x 16 rows
    int l = threadIdx.x & 63;
    float2 v = ((const float2*)(F + (size_t)row * D))[l];
    float ss = v.x * v.x + v.y * v.y;
#pragma unroll
    for (int off = 32; off > 0; off >>= 1) ss += __shfl_xor(ss, off);
    float sc = sqrtf(14.4269504089f / ss);  // 10 * log2(e), folded
    __hip_bfloat16 hx = __float2bfloat16(v.x * sc);
    __hip_bfloat16 hy = __float2bfloat16(v.y * sc);
    ushort2 u;
    u.x = *(unsigned short*)&hx;
    u.y = *(unsigned short*)&hy;
    ((ushort2*)(Fb + (size_t)row * D))[l] = u;
    if (blockIdx.x == 0 && threadIdx.x == 0) out[0] = 0.0f;  // for finalize atomics
}

// ---------------- sim: barrier-free, wave tile 16x64, MFMA 16x16x32 bf16 ----
// Grid (8 chunks, 128 row-blocks) x 256 thr = 1024 blocks = 4/CU exactly.
// Wave w owns rows [by*64 + w*16, +16); loops 16 col-tiles of 64 in its chunk.
__global__ __launch_bounds__(256, 4) void sim_kernel(
    const unsigned short* __restrict__ Fb, const int* __restrict__ labels,
    float* __restrict__ pE, float* __restrict__ pP) {
    const int chunk = blockIdx.x;        // 0..7   (1024-col chunk)
    const int by = blockIdx.y;           // 0..127 (64-row block)
    const int i0 = by * 64;
    const int t = threadIdx.x, w = t >> 6, l = t & 63;
    const int c = l & 15, quad = l >> 4;
    const int r0 = i0 + w * 16;          // this wave's 16 rows

    // A fragments: persistent, 4 x b128 = 16 VGPRs (rows r0+c, k-major 16B)
    short8 af[4];
    const unsigned short* arow = Fb + (size_t)(r0 + c) * D;
#pragma unroll
    for (int kk = 0; kk < 4; ++kk)
        af[kk] = *(const short8*)(arow + (kk * 4 + quad) * 8);

    int li[4];
#pragma unroll
    for (int r = 0; r < 4; ++r) li[r] = labels[r0 + quad * 4 + r];

    float RE[4] = {}, RP[4] = {};

#pragma unroll 2
    for (int s = 0; s < 16; ++s) {
        const int jt = chunk * 16 + s;   // global 64-col tile index
        const int j0 = jt * 64;
        int lj[4];
#pragma unroll
        for (int n = 0; n < 4; ++n) lj[n] = labels[j0 + n * 16 + c];

        f32x4 acc[4] = {};
#pragma unroll
        for (int kk = 0; kk < 4; ++kk) {
            short8 bf[4];
#pragma unroll
            for (int n = 0; n < 4; ++n)
                bf[n] = *(const short8*)&Fb[(size_t)(j0 + n * 16 + c) * D +
                                            (kk * 4 + quad) * 8];
#pragma unroll
            for (int n = 0; n < 4; ++n)
                acc[n] = __builtin_amdgcn_mfma_f32_16x16x32_bf16(
                    af[kk], bf[n], acc[n], 0, 0, 0);
        }

        // epilogue: C/D layout row = quad*4+r (+w*16), col = c (+n*16)
        if (jt == by) {  // diagonal tile (wave-uniform branch)
#pragma unroll
            for (int n = 0; n < 4; ++n)
#pragma unroll
                for (int r = 0; r < 4; ++r) {
                    float s2 = acc[n][r];
                    bool self = (w * 16 + quad * 4 + r) == (n * 16 + c);
                    bool pos = (li[r] == lj[n]) && !self;
                    RE[r] += self ? 0.0f : fast_exp2(s2);
                    RP[r] += pos ? s2 : 0.0f;
                }
        } else {
#pragma unroll
            for (int n = 0; n < 4; ++n)
#pragma unroll
                for (int r = 0; r < 4; ++r) {
                    float s2 = acc[n][r];
                    RE[r] += fast_exp2(s2);
                    RP[r] += (li[r] == lj[n]) ? s2 : 0.0f;
                }
        }
    }

    // reduce across the 16 c-lanes (bits 0..3 of lane id)
#pragma unroll
    for (int r = 0; r < 4; ++r) {
#pragma unroll
        for (int off = 1; off < 16; off <<= 1) {
            RE[r] += __shfl_xor(RE[r], off);
            RP[r] += __shfl_xor(RP[r], off);
        }
    }
    if (c == 0) {  // lanes 0,16,32,48 each own 4 rows -> plain stores, no RMW
#pragma unroll
        for (int r = 0; r < 4; ++r) {
            int row = r0 + quad * 4 + r;
            pE[row * 8 + chunk] = RE[r];
            pP[row * 8 + chunk] = RP[r];
        }
    }
}

// ---------------- finalize: hist in LDS, depth-8 partial sums ---------------
// Grid 128 blocks x 256 thr; block b owns rows [b*64, b*64+64).
__global__ void finalize_kernel(const float* __restrict__ pE,
                                const float* __restrict__ pP,
                                const int* __restrict__ labels,
                                float* __restrict__ out) {
    __shared__ int h[1024];
    int t = threadIdx.x;
#pragma unroll
    for (int i = 0; i < 4; ++i) h[t + i * 256] = 0;
    __syncthreads();
    for (int i = t; i < N; i += 256) atomicAdd(&h[labels[i]], 1);
    __syncthreads();

    float a = 0.0f;
    if (t < 64) {
        int row = blockIdx.x * 64 + t;
        int cnt = h[labels[row]] - 1;
        if (cnt > 0) {
            const float4* e = (const float4*)(pE + row * 8);
            const float4* p = (const float4*)(pP + row * 8);
            float4 e0 = e[0], e1 = e[1], p0 = p[0], p1 = p[1];
            float E = (e0.x + e0.y) + (e0.z + e0.w) +
                      (e1.x + e1.y) + (e1.z + e1.w);
            float P = (p0.x + p0.y) + (p0.z + p0.w) +
                      (p1.x + p1.y) + (p1.z + p1.w);
            a = __logf(E + 1e-9f) - 0.69314718056f * P / (float)cnt;
        }
#pragma unroll
        for (int off = 32; off > 0; off >>= 1) a += __shfl_xor(a, off);
        if (t == 0) atomicAdd(out, a * (1.0f / (float)N));
    }
}

extern "C" void kernel_launch(void* const* d_in, const int* in_sizes, int n_in,
                              void* d_out, int out_size, void* d_ws, size_t ws_size,
                              hipStream_t stream) {
    const float* F      = (const float*)d_in[0];
    const int*   labels = (const int*)d_in[1];
    float* out = (float*)d_out;

    unsigned short* Fb = (unsigned short*)d_ws;   // N*D bf16 = 2 MB
    float* pE = (float*)(Fb + (size_t)N * D);     // N*8 floats = 256 KB
    float* pP = pE + (size_t)N * 8;               // N*8 floats = 256 KB

    prep_kernel<<<N / 16, 1024, 0, stream>>>(F, Fb, out);
    sim_kernel<<<dim3(8, 128), 256, 0, stream>>>(Fb, labels, pE, pP);
    finalize_kernel<<<128, 256, 0, stream>>>(pE, pP, labels, out);
}

// Round 7
// 106.863 us; speedup vs baseline: 1.7142x; 1.7142x over previous
//
#include <hip/hip_runtime.h>
#include <hip/hip_bf16.h>
#include <math.h>

// SupCon loss, N=8192 D=128 fp32 in, scalar fp32 out.
// Round 7: A-fragments in registers (loaded once from global), B tiles
// double-buffered in LDS via global_load_lds (ONE barrier per tile: waves
// passing the top barrier have finished the previous tile's reads, so the
// next tile's DMA into the other buffer can issue immediately; its completion
// is enforced by the NEXT barrier's vmcnt(0) drain -- a full tile of compute
// in between). No atomics in sim: per-(row,chunk) partials are plain stores.
// R6 lesson: never load MFMA fragments straight from global (16-line scatter
// per instruction serializes the VMEM port). R4 lesson: no column atomics.
// Fb = f/||f|| * sqrt(10*log2e) -> MFMA acc is log2-domain: exp(sim)=exp2(acc).

constexpr int N = 8192;
constexpr int D = 128;

typedef __attribute__((ext_vector_type(8))) short short8;  // 8 bf16 = 4 VGPRs
typedef __attribute__((ext_vector_type(4))) float f32x4;

__device__ __forceinline__ float fast_exp2(float x) {
#if __has_builtin(__builtin_amdgcn_exp2f)
    return __builtin_amdgcn_exp2f(x);
#else
    return __expf(x * 0.69314718056f);
#endif
}

__device__ __forceinline__ void gload_lds16(const void* g, void* s) {
    __builtin_amdgcn_global_load_lds(
        (const __attribute__((address_space(1))) unsigned int*)g,
        (__attribute__((address_space(3))) unsigned int*)s, 16, 0, 0);
}

// ---------------- prep: bf16 rows scaled into log2 domain; zero out ---------
__global__ void prep_kernel(const float* __restrict__ F,
                            unsigned short* __restrict__ Fb,
                            float* __restrict__ out) {
    int row = blockIdx.x * 16 + (threadIdx.x >> 6);  // 512 blocks x 16 rows
    int l = threadIdx.x & 63;
    float2 v = ((const float2*)(F + (size_t)row * D))[l];
    float ss = v.x * v.x + v.y * v.y;
#pragma unroll
    for (int off = 32; off > 0; off >>= 1) ss += __shfl_xor(ss, off);
    float sc = sqrtf(14.4269504089f / ss);  // 10 * log2(e), folded
    __hip_bfloat16 hx = __float2bfloat16(v.x * sc);
    __hip_bfloat16 hy = __float2bfloat16(v.y * sc);
    ushort2 u;
    u.x = *(unsigned short*)&hx;
    u.y = *(unsigned short*)&hy;
    ((ushort2*)(Fb + (size_t)row * D))[l] = u;
    if (blockIdx.x == 0 && threadIdx.x == 0) out[0] = 0.0f;  // finalize atomics
}

// Stage one 64x128 bf16 B-tile (16 KB) with the whole 256-thread block.
// LDS dest is wave-uniform base + lane*16 (m104/m108): lane-contiguous.
// Source-side XOR swizzle: 16B-slot s' of row r holds k-block s'^(r&7), so
// compute-side ds_read_b128 spreads all 32 banks (2-way = free, m136).
__device__ __forceinline__ void stage_tile64(const unsigned short* __restrict__ src,
                                             unsigned short* dst,
                                             int w, int lr, int lq) {
#pragma unroll
    for (int it = 0; it < 4; ++it) {
        int a = it * 4 + w;       // 1 KB group 0..15
        int r = a * 4 + lr;       // tile row 0..63
        int q = lq ^ (r & 7);     // swizzled source 16B-block
        gload_lds16(src + (size_t)r * D + q * 8, dst + a * 512);
    }
}

// ---------------- sim: 128 rows x 512-col chunk per block -------------------
// Grid (16 chunks, 64 row-blocks) x 256 thr = 1024 blocks = exactly 4/CU.
// Wave w owns rows [i0+w*32, +32): af[2][4] regs; all waves share the B tile.
__global__ __launch_bounds__(256, 4) void sim_kernel(
    const unsigned short* __restrict__ Fb, const int* __restrict__ labels,
    float* __restrict__ pE, float* __restrict__ pP) {
    __shared__ unsigned short Bt[2][64 * D];  // 2 x 16 KB

    const int chunk = blockIdx.x;   // 0..15 (512-col chunk = 8 tiles of 64)
    const int bb = blockIdx.y;      // 0..63 (128-row block)
    const int i0 = bb * 128;
    const int t = threadIdx.x, w = t >> 6, l = t & 63;
    const int c = l & 15, quad = l >> 4;

    // A fragments: persistent, 2 row-bands x 4 k-steps = 32 VGPRs
    short8 af[2][4];
    int li[2][4];
#pragma unroll
    for (int mb = 0; mb < 2; ++mb) {
        const unsigned short* ar = Fb + (size_t)(i0 + w * 32 + mb * 16 + c) * D;
#pragma unroll
        for (int kk = 0; kk < 4; ++kk)
            af[mb][kk] = *(const short8*)(ar + (kk * 4 + quad) * 8);
#pragma unroll
        for (int r = 0; r < 4; ++r)
            li[mb][r] = labels[i0 + w * 32 + mb * 16 + quad * 4 + r];
    }

    stage_tile64(Fb + (size_t)(chunk * 8) * 64 * D, Bt[0], w, quad, c);

    float RE[2][4] = {}, RP[2][4] = {};
    const int myjt = bb * 2 + (w >> 1);  // this wave's diagonal 64-col tile

    for (int s = 0; s < 8; ++s) {
        const int jt = chunk * 8 + s, j0 = jt * 64, p = s & 1;
        __syncthreads();  // DMA(s) drained (compiler vmcnt(0)); waves synced
        if (s < 7)        // issue DMA(s+1) NOW -- full tile of compute to drain
            stage_tile64(Fb + (size_t)(jt + 1) * 64 * D, Bt[p ^ 1], w, quad, c);

        int lj[4];
#pragma unroll
        for (int n = 0; n < 4; ++n) lj[n] = labels[j0 + n * 16 + c];

        f32x4 acc[2][4] = {};
#pragma unroll
        for (int kk = 0; kk < 4; ++kk) {
            int sl = (kk * 4 + quad) ^ (c & 7);  // undo swizzle (row&7 == c&7)
            short8 bf[4];
#pragma unroll
            for (int n = 0; n < 4; ++n)
                bf[n] = *(const short8*)&Bt[p][(n * 16 + c) * D + sl * 8];
#pragma unroll
            for (int mb = 0; mb < 2; ++mb)
#pragma unroll
                for (int n = 0; n < 4; ++n)
                    acc[mb][n] = __builtin_amdgcn_mfma_f32_16x16x32_bf16(
                        af[mb][kk], bf[n], acc[mb][n], 0, 0, 0);
        }

        // epilogue: C/D row = quad*4+r (+band), col = c (+n*16)
        if (jt == myjt) {  // wave-uniform diagonal branch
#pragma unroll
            for (int mb = 0; mb < 2; ++mb)
#pragma unroll
                for (int n = 0; n < 4; ++n)
#pragma unroll
                    for (int r = 0; r < 4; ++r) {
                        float s2 = acc[mb][n][r];
                        bool self = ((w & 1) * 32 + mb * 16 + quad * 4 + r) ==
                                    (n * 16 + c);
                        bool pos = (li[mb][r] == lj[n]) && !self;
                        RE[mb][r] += self ? 0.0f : fast_exp2(s2);
                        RP[mb][r] += pos ? s2 : 0.0f;
                    }
        } else {
#pragma unroll
            for (int mb = 0; mb < 2; ++mb)
#pragma unroll
                for (int n = 0; n < 4; ++n)
#pragma unroll
                    for (int r = 0; r < 4; ++r) {
                        float s2 = acc[mb][n][r];
                        RE[mb][r] += fast_exp2(s2);
                        RP[mb][r] += (li[mb][r] == lj[n]) ? s2 : 0.0f;
                    }
        }
    }

    // reduce across the 16 c-lanes; then exclusive plain stores (no RMW)
#pragma unroll
    for (int mb = 0; mb < 2; ++mb)
#pragma unroll
        for (int r = 0; r < 4; ++r) {
#pragma unroll
            for (int off = 1; off < 16; off <<= 1) {
                RE[mb][r] += __shfl_xor(RE[mb][r], off);
                RP[mb][r] += __shfl_xor(RP[mb][r], off);
            }
        }
    if (c == 0) {
#pragma unroll
        for (int mb = 0; mb < 2; ++mb)
#pragma unroll
            for (int r = 0; r < 4; ++r) {
                int row = i0 + w * 32 + mb * 16 + quad * 4 + r;
                pE[row * 16 + chunk] = RE[mb][r];
                pP[row * 16 + chunk] = RP[mb][r];
            }
    }
}

// ---------------- finalize: hist in LDS, depth-16 partial sums --------------
// Grid 128 blocks x 256 thr; block b owns rows [b*64, b*64+64).
__global__ void finalize_kernel(const float* __restrict__ pE,
                                const float* __restrict__ pP,
                                const int* __restrict__ labels,
                                float* __restrict__ out) {
    __shared__ int h[1024];
    int t = threadIdx.x;
#pragma unroll
    for (int i = 0; i < 4; ++i) h[t + i * 256] = 0;
    __syncthreads();
    for (int i = t; i < N; i += 256) atomicAdd(&h[labels[i]], 1);
    __syncthreads();

    float a = 0.0f;
    if (t < 64) {
        int row = blockIdx.x * 64 + t;
        int cnt = h[labels[row]] - 1;
        if (cnt > 0) {
            const float4* e = (const float4*)(pE + (size_t)row * 16);
            const float4* p = (const float4*)(pP + (size_t)row * 16);
            float E = 0.0f, P = 0.0f;
#pragma unroll
            for (int i = 0; i < 4; ++i) {
                float4 ev = e[i], pv = p[i];
                E += (ev.x + ev.y) + (ev.z + ev.w);
                P += (pv.x + pv.y) + (pv.z + pv.w);
            }
            a = __logf(E + 1e-9f) - 0.69314718056f * P / (float)cnt;
        }
#pragma unroll
        for (int off = 32; off > 0; off >>= 1) a += __shfl_xor(a, off);
        if (t == 0) atomicAdd(out, a * (1.0f / (float)N));
    }
}

extern "C" void kernel_launch(void* const* d_in, const int* in_sizes, int n_in,
                              void* d_out, int out_size, void* d_ws, size_t ws_size,
                              hipStream_t stream) {
    const float* F      = (const float*)d_in[0];
    const int*   labels = (const int*)d_in[1];
    float* out = (float*)d_out;

    unsigned short* Fb = (unsigned short*)d_ws;   // N*D bf16 = 2 MB
    float* pE = (float*)(Fb + (size_t)N * D);     // N*16 floats = 512 KB
    float* pP = pE + (size_t)N * 16;              // N*16 floats = 512 KB

    prep_kernel<<<N / 16, 1024, 0, stream>>>(F, Fb, out);
    sim_kernel<<<dim3(16, 64), 256, 0, stream>>>(Fb, labels, pE, pP);
    finalize_kernel<<<128, 256, 0, stream>>>(pE, pP, labels, out);
}